// Round 10
// baseline (198.675 us; speedup 1.0000x reference)
//
#include <hip/hip_runtime.h>
#include <hip/hip_bf16.h>

#define DIM 768
#define NTOK 32768
#define TTOK 16
#define NADP 256   // padded concat adapter dim (240 used)

typedef __attribute__((ext_vector_type(8))) short short8;
typedef __attribute__((ext_vector_type(4))) float f32x4;

__device__ __forceinline__ unsigned short f2bf(float f) {
  union { float f; unsigned int u; } v; v.f = f;
  unsigned int u = v.u;
  return (unsigned short)((u + 0x7fffu + ((u >> 16) & 1u)) >> 16);
}
__device__ __forceinline__ float bf2f(unsigned short u) {
  union { unsigned int u; float f; } v; v.u = ((unsigned int)u) << 16; return v.f;
}

// ---- build concatenated bf16 weights:
// wdTc [256][768]: row n = adapter col (expert-concat), col k.  wdTc[n][k]=Wd_e[k][n-off]
// wuTc [768][256]: row dcol, col kk = adapter col.              wuTc[d][kk]=Wu_e[kk-off][d]
// bdc  [256]: concat down bias (pad 0)
__global__ void prep_kernel(const float* __restrict__ Wd0, const float* __restrict__ Wd1,
                            const float* __restrict__ Wd2, const float* __restrict__ Wd3,
                            const float* __restrict__ Wu0, const float* __restrict__ Wu1,
                            const float* __restrict__ Wu2, const float* __restrict__ Wu3,
                            const float* __restrict__ bd0, const float* __restrict__ bd1,
                            const float* __restrict__ bd2, const float* __restrict__ bd3,
                            unsigned short* __restrict__ wdTc, unsigned short* __restrict__ wuTc,
                            float* __restrict__ bdc) {
  const int stride = gridDim.x * 256;
  int start = blockIdx.x * 256 + threadIdx.x;
  // section 1: wdTc
  for (int i = start; i < NADP * DIM; i += stride) {
    int n = i / DIM, k = i - n * DIM;
    float v = 0.f;
    if (n < 16)       v = Wd0[k * 16 + n];
    else if (n < 48)  v = Wd1[k * 32 + (n - 16)];
    else if (n < 112) v = Wd2[k * 64 + (n - 48)];
    else if (n < 240) v = Wd3[k * 128 + (n - 112)];
    wdTc[i] = f2bf(v);
  }
  // section 2: wuTc
  for (int i = start; i < DIM * NADP; i += stride) {
    int d = i >> 8, kk = i & 255;
    float v = 0.f;
    if (kk < 16)       v = Wu0[kk * DIM + d];
    else if (kk < 48)  v = Wu1[(kk - 16) * DIM + d];
    else if (kk < 112) v = Wu2[(kk - 48) * DIM + d];
    else if (kk < 240) v = Wu3[(kk - 112) * DIM + d];
    wuTc[i] = f2bf(v);
  }
  // section 3: bdc
  for (int n = start; n < NADP; n += stride) {
    float v = 0.f;
    if (n < 16)       v = bd0[n];
    else if (n < 48)  v = bd1[n - 16];
    else if (n < 112) v = bd2[n - 48];
    else if (n < 240) v = bd3[n - 112];
    bdc[n] = v;
  }
}

// ---- fused dense masked-adapter: one block = 16 sequential tokens.
// stage x -> LDS bf16 | GEMM1 (K=768, N=256) + mask by expert slice -> dn |
// GEMM2 (K=256, N=768) -> OL | burst out = OL + bu_e + x
__global__ __launch_bounds__(256, 4) void moe_main(
    const float* __restrict__ x, const int* __restrict__ mask,
    const unsigned short* __restrict__ wdTc, const unsigned short* __restrict__ wuTc,
    const float* __restrict__ bdc,
    const float* __restrict__ bu0, const float* __restrict__ bu1,
    const float* __restrict__ bu2, const float* __restrict__ bu3,
    float* __restrict__ out) {
  __shared__ unsigned short xsol[TTOK * 776];  // x tile (pitch 776) / OL out tile (pitch 772)
  __shared__ unsigned short dn[TTOK][264];
  __shared__ int me[TTOK];
  #define XS(r) (xsol + (r) * 776)
  #define OL(r) (xsol + (r) * 772)

  int tid = threadIdx.x, wv = tid >> 6, lane = tid & 63;
  int lrow = lane & 15, kg = lane >> 4;
  int t0 = blockIdx.x * TTOK;

  // ---- stage-in: wave wv bursts rows wv*4..+3 (3x 1KB contiguous each)
  float4 v[4][3];
  {
    const float* src = x + (size_t)(t0 + wv * 4) * DIM + lane * 4;
    #pragma unroll
    for (int i = 0; i < 4; ++i)
      #pragma unroll
      for (int j = 0; j < 3; ++j)
        v[i][j] = *(const float4*)(src + i * DIM + j * 256);
  }
  if (tid < TTOK) me[tid] = mask[t0 + tid] & 3;
  #pragma unroll
  for (int i = 0; i < 4; ++i) {
    int r = wv * 4 + i;
    #pragma unroll
    for (int j = 0; j < 3; ++j) {
      ushort4 b;
      b.x = f2bf(v[i][j].x); b.y = f2bf(v[i][j].y);
      b.z = f2bf(v[i][j].z); b.w = f2bf(v[i][j].w);
      *(ushort4*)(XS(r) + j * 256 + lane * 4) = b;
    }
  }
  __syncthreads();

  // ---- GEMM1: dn = mask(relu(x @ Wd_cat + bd_cat)); wave owns 4 n-tiles
  {
    f32x4 acc[4];
    #pragma unroll
    for (int nb = 0; nb < 4; ++nb) acc[nb] = f32x4{0.f, 0.f, 0.f, 0.f};
    const unsigned short* xr = XS(lrow) + kg * 8;
    const unsigned short* wr = wdTc + (size_t)(wv * 64 + lrow) * DIM + kg * 8;
    #pragma unroll 4
    for (int ks = 0; ks < 24; ++ks) {
      short8 a = *(const short8*)(xr + ks * 32);
      #pragma unroll
      for (int nb = 0; nb < 4; ++nb) {
        short8 b = *(const short8*)(wr + (size_t)nb * 16 * DIM + ks * 32);
        acc[nb] = __builtin_amdgcn_mfma_f32_16x16x32_bf16(a, b, acc[nb], 0, 0, 0);
      }
    }
    const int OFF[4] = {0, 16, 48, 112};
    const int DSZ[4] = {16, 32, 64, 128};
    #pragma unroll
    for (int nb = 0; nb < 4; ++nb) {
      int kcol = (wv * 4 + nb) * 16 + lrow;
      float bdv = bdc[kcol];
      #pragma unroll
      for (int r = 0; r < 4; ++r) {
        int tt = kg * 4 + r;
        int e = me[tt];
        bool keep = (unsigned)(kcol - OFF[e]) < (unsigned)DSZ[e];
        float val = keep ? fmaxf(acc[nb][r] + bdv, 0.f) : 0.f;
        dn[tt][kcol] = f2bf(val);
      }
    }
  }
  __syncthreads();

  // ---- GEMM2: up = dn @ Wu_cat -> OL (bf16); wave owns 12 n-tiles (192 dcols)
  {
    short8 afr[8];
    #pragma unroll
    for (int ks = 0; ks < 8; ++ks)
      afr[ks] = *(const short8*)&dn[lrow][ks * 32 + kg * 8];
    const unsigned short* wr = wuTc + (size_t)(wv * 192 + lrow) * NADP + kg * 8;
    #pragma unroll 3
    for (int nn = 0; nn < 12; ++nn) {
      f32x4 c = {0.f, 0.f, 0.f, 0.f};
      #pragma unroll
      for (int ks = 0; ks < 8; ++ks) {
        short8 b = *(const short8*)(wr + (size_t)nn * 16 * NADP + ks * 32);
        c = __builtin_amdgcn_mfma_f32_16x16x32_bf16(afr[ks], b, c, 0, 0, 0);
      }
      int dcol = (wv * 12 + nn) * 16 + lrow;
      #pragma unroll
      for (int r = 0; r < 4; ++r)
        OL(kg * 4 + r)[dcol] = f2bf(c[r]);
    }
  }
  __syncthreads();

  // ---- stage-out: wave wv bursts rows wv*4..+3: out = OL + bu_e + x
  #pragma unroll
  for (int i = 0; i < 4; ++i) {
    int r = wv * 4 + i;
    int t = t0 + r;
    int e = me[r];
    const float* bup = (e == 0) ? bu0 : (e == 1) ? bu1 : (e == 2) ? bu2 : bu3;
    const float* xsrc = x + (size_t)t * DIM;
    float* dst = out + (size_t)t * DIM;
    #pragma unroll
    for (int j = 0; j < 3; ++j) {
      int c = j * 256 + lane * 4;
      float4 xv = *(const float4*)(xsrc + c);
      float4 bv = *(const float4*)(bup + c);
      ushort4 ub = *(const ushort4*)(OL(r) + c);
      float4 o;
      o.x = xv.x + bv.x + bf2f(ub.x);
      o.y = xv.y + bv.y + bf2f(ub.y);
      o.z = xv.z + bv.z + bf2f(ub.z);
      o.w = xv.w + bv.w + bf2f(ub.w);
      *(float4*)(dst + c) = o;
    }
  }
  #undef XS
  #undef OL
}

extern "C" void kernel_launch(void* const* d_in, const int* in_sizes, int n_in,
                              void* d_out, int out_size, void* d_ws, size_t ws_size,
                              hipStream_t stream) {
  const float* x = (const float*)d_in[0];
  const int* mask = (const int*)d_in[1];
  const float* Wd[4]; const float* bd[4]; const float* Wu[4]; const float* bu[4];
  for (int i = 0; i < 4; ++i) {
    Wd[i] = (const float*)d_in[2 + 4 * i];
    bd[i] = (const float*)d_in[3 + 4 * i];
    Wu[i] = (const float*)d_in[4 + 4 * i];
    bu[i] = (const float*)d_in[5 + 4 * i];
  }
  char* ws = (char*)d_ws;
  unsigned short* wdTc = (unsigned short*)ws;             // 256*768*2 = 393216 B
  unsigned short* wuTc = (unsigned short*)(ws + 393216);  // 768*256*2 = 393216 B
  float* bdc = (float*)(ws + 786432);                     // 1024 B

  prep_kernel<<<256, 256, 0, stream>>>(Wd[0], Wd[1], Wd[2], Wd[3],
                                       Wu[0], Wu[1], Wu[2], Wu[3],
                                       bd[0], bd[1], bd[2], bd[3],
                                       wdTc, wuTc, bdc);
  moe_main<<<NTOK / TTOK, 256, 0, stream>>>(x, mask, wdTc, wuTc, bdc,
                                            bu[0], bu[1], bu[2], bu[3],
                                            (float*)d_out);
}

// Round 11
// 96.833 us; speedup vs baseline: 2.0517x; 2.0517x over previous
//
#include <hip/hip_runtime.h>
#include <hip/hip_bf16.h>

#define DIM 768
#define NTOK 32768
#define TTOK 16
#define NBLK 128
#define GRID_MAIN 1024
#define XP 772   // xs/OL pitch in shorts (OL == XS, residual folded in phase B)

typedef __attribute__((ext_vector_type(8))) short short8;
typedef __attribute__((ext_vector_type(4))) float f32x4;

__device__ __forceinline__ unsigned short f2bf(float f) {
  union { float f; unsigned int u; } v; v.f = f;
  unsigned int u = v.u;
  return (unsigned short)((u + 0x7fffu + ((u >> 16) & 1u)) >> 16);
}
__device__ __forceinline__ float bf2f(unsigned short u) {
  union { unsigned int u; float f; } v; v.u = ((unsigned int)u) << 16; return v.f;
}

// LDS-only barrier: does NOT drain vmcnt — global prefetch/stores stay in flight.
// All cross-wave deps in the tile are through LDS, so this is sufficient.
__device__ __forceinline__ void barrier_lds() {
  asm volatile("s_waitcnt lgkmcnt(0)" ::: "memory");
  __builtin_amdgcn_s_barrier();
  asm volatile("" ::: "memory");
}

// ---- pass 1: per-(block,expert) histogram
__global__ void hist_kernel(const int* __restrict__ mask, int* __restrict__ hist) {
  int tid = threadIdx.x, b = blockIdx.x;
  int gid = b * 256 + tid;
  int wv = tid >> 6, lane = tid & 63;
  int e = mask[gid] & 3;
  __shared__ int wcnt[4][4];
  #pragma unroll
  for (int q = 0; q < 4; ++q) {
    unsigned long long m = __ballot(e == q);
    if (lane == 0) wcnt[wv][q] = __popcll(m);
  }
  __syncthreads();
  if (tid < 4)
    hist[tid * NBLK + b] = wcnt[0][tid] + wcnt[1][tid] + wcnt[2][tid] + wcnt[3][tid];
}

// ---- pass 2: single-wave exclusive scan over 512 (expert-major) entries
__global__ void scan_kernel(const int* __restrict__ hist, int* __restrict__ base,
                            int* __restrict__ meta) {
  int lane = threadIdx.x;  // 64 threads
  int v[8];
  int lsum = 0;
  #pragma unroll
  for (int j = 0; j < 8; ++j) {
    int t = hist[lane * 8 + j];
    v[j] = lsum; lsum += t;
  }
  int inc = lsum;
  #pragma unroll
  for (int d = 1; d < 64; d <<= 1) {
    int u = __shfl_up(inc, d);
    if (lane >= d) inc += u;
  }
  int excl = inc - lsum;
  #pragma unroll
  for (int j = 0; j < 8; ++j) base[lane * 8 + j] = excl + v[j];
  __syncthreads();
  if (lane == 0) {
    int est[5];
    #pragma unroll
    for (int e = 0; e < 4; ++e) est[e] = base[e * NBLK];
    est[4] = NTOK;
    int s = 0;
    #pragma unroll
    for (int e = 0; e < 5; ++e) meta[e] = est[e];
    #pragma unroll
    for (int e = 0; e < 4; ++e) {
      meta[8 + e] = s;
      s += (est[e + 1] - est[e] + TTOK - 1) / TTOK;
    }
    meta[12] = s;
  }
}

// ---- pass 3: scatter tokens to exact sorted positions
__global__ void scatter_kernel(const int* __restrict__ mask, const int* __restrict__ base,
                               int* __restrict__ lists) {
  int tid = threadIdx.x, b = blockIdx.x;
  int gid = b * 256 + tid;
  int wv = tid >> 6, lane = tid & 63;
  int e = mask[gid] & 3;
  __shared__ int wcnt[4][4];
  __shared__ int wbase[4][4];
  unsigned long long lt = (1ull << lane) - 1ull;
  int rank = 0;
  #pragma unroll
  for (int q = 0; q < 4; ++q) {
    unsigned long long m = __ballot(e == q);
    if (e == q) rank = __popcll(m & lt);
    if (lane == 0) wcnt[wv][q] = __popcll(m);
  }
  __syncthreads();
  if (tid < 4) {
    int s = 0;
    #pragma unroll
    for (int w2 = 0; w2 < 4; ++w2) { int c = wcnt[w2][tid]; wbase[w2][tid] = s; s += c; }
  }
  __syncthreads();
  lists[base[e * NBLK + b] + wbase[wv][e] + rank] = gid;
}

// ---- weight repack to bf16 (WdT [ds][768], WuT [768][KP] zero-padded)
__global__ void prep_kernel(const float* __restrict__ Wd0, const float* __restrict__ Wd1,
                            const float* __restrict__ Wd2, const float* __restrict__ Wd3,
                            const float* __restrict__ Wu0, const float* __restrict__ Wu1,
                            const float* __restrict__ Wu2, const float* __restrict__ Wu3,
                            unsigned short* __restrict__ wdT, unsigned short* __restrict__ wuT) {
  int e = blockIdx.x;
  int ds = 16 << e;
  int lgK = (e == 0) ? 5 : (4 + e);
  int KP = 1 << lgK;
  const float* Wd = (e == 0) ? Wd0 : (e == 1) ? Wd1 : (e == 2) ? Wd2 : Wd3;
  const float* Wu = (e == 0) ? Wu0 : (e == 1) ? Wu1 : (e == 2) ? Wu2 : Wu3;
  const int WOFF[4] = {0, 12288, 36864, 86016};
  const int UOFF[4] = {0, 24576, 49152, 98304};
  int stride = gridDim.y * 256;
  int start = blockIdx.y * 256 + threadIdx.x;
  int nd = ds * DIM;
  for (int i = start; i < nd; i += stride) {
    int k = i / DIM, d = i - k * DIM;
    wdT[WOFF[e] + i] = f2bf(Wd[d * ds + k]);
  }
  int nu = DIM << lgK;
  for (int i = start; i < nu; i += stride) {
    int dc = i >> lgK, k = i & (KP - 1);
    wuT[UOFF[e] + i] = (k < ds) ? f2bf(Wu[k * DIM + dc]) : (unsigned short)0;
  }
}

__device__ __forceinline__ int expert_of(int w, const int* __restrict__ ts) {
  return (w >= ts[2]) ? ((w >= ts[3]) ? 3 : 2) : ((w >= ts[1]) ? 1 : 0);
}

// Full next-tile prefetch: 4 token ids + all 4 rows (12 float4/wave).
struct Pref {
  float4 v[12];
  int tk[4];
};

__device__ __forceinline__ void issue_prefetch(
    int w, int wv, int lane,
    const int* __restrict__ meta, const int* __restrict__ lists,
    const float* __restrict__ x, Pref& p) {
  const int* ts = meta + 8;
  int e = expert_of(w, ts);
  int base = (w - ts[e]) * TTOK;
  int cnt = meta[e + 1] - meta[e];
  const int* listsE = lists + meta[e];
  #pragma unroll
  for (int i = 0; i < 4; ++i) {
    int r = base + wv * 4 + i;
    p.tk[i] = (r < cnt) ? listsE[r] : -1;
  }
  #pragma unroll
  for (int i = 0; i < 4; ++i) {
    int t = p.tk[i];
    const float* src = x + (size_t)((t >= 0) ? t : 0) * DIM;
    #pragma unroll
    for (int j = 0; j < 3; ++j) {
      float4 vv = {0.f, 0.f, 0.f, 0.f};
      if (t >= 0) vv = *(const float4*)(src + j * 256 + lane * 4);
      p.v[i * 3 + j] = vv;
    }
  }
}

// ---- per-tile compute (R6 body, LDS-only barriers, residual folded in B)
template <int E>
__device__ __forceinline__ void moe_tile(
    int wv, int lane, int tid,
    const unsigned short* __restrict__ wdT, const unsigned short* __restrict__ wuT,
    const float* __restrict__ bd, const float* __restrict__ bu,
    float* __restrict__ out, const int mytk[4],
    unsigned short* __restrict__ xsol, float* __restrict__ dnpart,
    unsigned short (*dn)[136]) {
  constexpr int DS = 16 << E;
  constexpr int KP = (E == 0) ? 32 : DS;
  constexpr int NTA = DS / 16;
  constexpr int SPLIT_N = (NTA < 4) ? NTA : 4;   // 1,2,4,4
  constexpr int SPLIT_K = 4 / SPLIT_N;           // 4,2,1,1
  constexpr int NTB = NTA / SPLIT_N;             // 1,1,1,2
  constexpr int KLEN = DIM / SPLIT_K;            // 192,384,768,768
  constexpr int KB = KP / 32;                    // 1,1,2,4
  constexpr int WOFF[4] = {0, 12288, 36864, 86016};
  constexpr int UOFF[4] = {0, 24576, 49152, 98304};
  const unsigned short* wd = wdT + WOFF[E];
  const unsigned short* wu = wuT + UOFF[E];

  int lrow = lane & 15, kg = lane >> 4;

  if (SPLIT_K > 1) {
    for (int i = tid; i < TTOK * DS; i += 256) dnpart[i] = 0.f;
  }
  barrier_lds();   // xs conversion (all waves) + dnpart zero visible

  // ---- phase A: dn = relu(X @ Wd + bd), A-frags from LDS
  int nsub = wv % SPLIT_N, ksub = wv / SPLIT_N;
  int d_base = ksub * KLEN;

  f32x4 acc[NTB];
  #pragma unroll
  for (int nb = 0; nb < NTB; ++nb) acc[nb] = f32x4{0.f, 0.f, 0.f, 0.f};

  for (int d0 = 0; d0 < KLEN; d0 += 64) {
    #pragma unroll
    for (int u = 0; u < 2; ++u) {
      int d = d_base + d0 + u * 32;
      short8 a = *(const short8*)(xsol + lrow * XP + d + kg * 8);
      #pragma unroll
      for (int nb = 0; nb < NTB; ++nb) {
        int n = nsub * NTB + nb;
        short8 b = *(const short8*)(wd + (size_t)(n * 16 + lrow) * DIM + d + kg * 8);
        acc[nb] = __builtin_amdgcn_mfma_f32_16x16x32_bf16(a, b, acc[nb], 0, 0, 0);
      }
    }
  }

  if (SPLIT_K > 1) {
    #pragma unroll
    for (int nb = 0; nb < NTB; ++nb) {
      int kc = (nsub * NTB + nb) * 16 + lrow;
      #pragma unroll
      for (int r = 0; r < 4; ++r)
        atomicAdd(&dnpart[(kg * 4 + r) * DS + kc], acc[nb][r]);
    }
    barrier_lds();
    for (int i = tid; i < TTOK * KP; i += 256) {
      int tt = i / KP, k = i - tt * KP;
      float v = (k < DS) ? fmaxf(dnpart[tt * DS + k] + bd[k], 0.f) : 0.f;
      dn[tt][k] = f2bf(v);
    }
  } else {
    #pragma unroll
    for (int nb = 0; nb < NTB; ++nb) {
      int kc = (nsub * NTB + nb) * 16 + lrow;
      float bv = bd[kc];
      #pragma unroll
      for (int r = 0; r < 4; ++r)
        dn[kg * 4 + r][kc] = f2bf(fmaxf(acc[nb][r] + bv, 0.f));
    }
  }
  barrier_lds();

  // ---- phase B: up = dn @ Wu + bu + x(bf16, from xs) -> OL (== XS, in place)
  short8 afr[KB];
  #pragma unroll
  for (int k = 0; k < KB; ++k) afr[k] = *(const short8*)&dn[lrow][k * 32 + kg * 8];

  #pragma unroll 3
  for (int nn = 0; nn < 12; ++nn) {
    int n = wv * 12 + nn;
    f32x4 c = {0.f, 0.f, 0.f, 0.f};
    #pragma unroll
    for (int k = 0; k < KB; ++k) {
      short8 b = *(const short8*)(wu + (size_t)(n * 16 + lrow) * KP + k * 32 + kg * 8);
      c = __builtin_amdgcn_mfma_f32_16x16x32_bf16(afr[k], b, c, 0, 0, 0);
    }
    int dcol = n * 16 + lrow;
    float bv = bu[dcol];
    #pragma unroll
    for (int r = 0; r < 4; ++r) {
      int t = kg * 4 + r;
      unsigned short* cell = xsol + t * XP + dcol;
      float xr = bf2f(*cell);               // residual (bf16 x)
      *cell = f2bf(c[r] + bv + xr);         // same thread read->write, in order
    }
  }
  barrier_lds();

  // ---- stage-out: wave wv bursts its 4 rows: out = OL (f32 stores)
  #pragma unroll
  for (int i = 0; i < 4; ++i) {
    int r = wv * 4 + i;
    int t = mytk[i];
    if (t < 0) continue;
    float* dst = out + (size_t)t * DIM;
    #pragma unroll
    for (int j = 0; j < 3; ++j) {
      int c = j * 256 + lane * 4;
      ushort4 ub = *(const ushort4*)(xsol + r * XP + c);
      float4 o;
      o.x = bf2f(ub.x); o.y = bf2f(ub.y); o.z = bf2f(ub.z); o.w = bf2f(ub.w);
      *(float4*)(dst + c) = o;
    }
  }
  barrier_lds();   // OL reads drained before next tile's convert overwrites xs
}

__global__ __launch_bounds__(256, 4) void moe_main(
    const float* __restrict__ x,
    const int* __restrict__ meta, const int* __restrict__ lists,
    const unsigned short* __restrict__ wdT, const unsigned short* __restrict__ wuT,
    const float* __restrict__ bd0, const float* __restrict__ bd1,
    const float* __restrict__ bd2, const float* __restrict__ bd3,
    const float* __restrict__ bu0, const float* __restrict__ bu1,
    const float* __restrict__ bu2, const float* __restrict__ bu3,
    float* __restrict__ out) {
  __shared__ unsigned short xsol[TTOK * XP];
  __shared__ float dnpart[TTOK * 32];
  __shared__ unsigned short dn[TTOK][136];
  int tid = threadIdx.x, wv = tid >> 6, lane = tid & 63;
  const int* ts = meta + 8;
  int ntiles = ts[4];
  int w = blockIdx.x;
  if (w >= ntiles) return;

  Pref p;
  issue_prefetch(w, wv, lane, meta, lists, x, p);

  // desync same-CU cohorts {b, b+256, b+512, b+768}: 0/1.7/3.4/5.1 us skew
  int cohort = blockIdx.x >> 8;
  for (int i = 0; i < cohort; ++i) __builtin_amdgcn_s_sleep(64);

  for (; w < ntiles; w += GRID_MAIN) {
    // ---- convert prefetched tile -> LDS bf16 (waits only on p's loads)
    #pragma unroll
    for (int i = 0; i < 4; ++i) {
      int r = wv * 4 + i;
      #pragma unroll
      for (int j = 0; j < 3; ++j) {
        float4 vv = p.v[i * 3 + j];
        ushort4 b;
        b.x = f2bf(vv.x); b.y = f2bf(vv.y); b.z = f2bf(vv.z); b.w = f2bf(vv.w);
        *(ushort4*)(xsol + r * XP + j * 256 + lane * 4) = b;
      }
    }
    int mytk[4];
    #pragma unroll
    for (int i = 0; i < 4; ++i) mytk[i] = p.tk[i];

    // ---- issue next tile's prefetch; stays in flight across ALL barriers
    int wn = w + GRID_MAIN;
    if (wn < ntiles) issue_prefetch(wn, wv, lane, meta, lists, x, p);

    int e = expert_of(w, ts);
    if (e == 0)
      moe_tile<0>(wv, lane, tid, wdT, wuT, bd0, bu0, out, mytk, xsol, dnpart, dn);
    else if (e == 1)
      moe_tile<1>(wv, lane, tid, wdT, wuT, bd1, bu1, out, mytk, xsol, dnpart, dn);
    else if (e == 2)
      moe_tile<2>(wv, lane, tid, wdT, wuT, bd2, bu2, out, mytk, xsol, dnpart, dn);
    else
      moe_tile<3>(wv, lane, tid, wdT, wuT, bd3, bu3, out, mytk, xsol, dnpart, dn);
  }
}

extern "C" void kernel_launch(void* const* d_in, const int* in_sizes, int n_in,
                              void* d_out, int out_size, void* d_ws, size_t ws_size,
                              hipStream_t stream) {
  const float* x = (const float*)d_in[0];
  const int* mask = (const int*)d_in[1];
  const float* Wd[4]; const float* bd[4]; const float* Wu[4]; const float* bu[4];
  for (int i = 0; i < 4; ++i) {
    Wd[i] = (const float*)d_in[2 + 4 * i];
    bd[i] = (const float*)d_in[3 + 4 * i];
    Wu[i] = (const float*)d_in[4 + 4 * i];
    bu[i] = (const float*)d_in[5 + 4 * i];
  }
  char* ws = (char*)d_ws;
  int* hist = (int*)ws;                                  // 2048 B
  int* base = (int*)(ws + 2048);                         // 2048 B
  int* meta = (int*)(ws + 4096);                         // 64 B
  int* lists = (int*)(ws + 4352);                        // 131072 B (sorted, concatenated)
  unsigned short* wdT = (unsigned short*)(ws + 135424);  // 368640 B
  unsigned short* wuT = (unsigned short*)(ws + 504064);  // 393216 B

  hist_kernel<<<NBLK, 256, 0, stream>>>(mask, hist);
  scan_kernel<<<1, 64, 0, stream>>>(hist, base, meta);
  scatter_kernel<<<NBLK, 256, 0, stream>>>(mask, base, lists);
  prep_kernel<<<dim3(4, 32), 256, 0, stream>>>(Wd[0], Wd[1], Wd[2], Wd[3],
                                               Wu[0], Wu[1], Wu[2], Wu[3], wdT, wuT);
  moe_main<<<GRID_MAIN, 256, 0, stream>>>(x, meta, lists, wdT, wuT,
                                          bd[0], bd[1], bd[2], bd[3],
                                          bu[0], bu[1], bu[2], bu[3],
                                          (float*)d_out);
}